// Round 18
// baseline (1118.759 us; speedup 1.0000x reference)
//
#include <hip/hip_runtime.h>

#define PAD_IDX 0

typedef __attribute__((ext_vector_type(8))) short short8;
typedef __attribute__((ext_vector_type(4))) float f32x4;

// ---------- helpers ----------
__device__ __forceinline__ unsigned short f32_to_bf16_rne(float f) {
  unsigned int u = __builtin_bit_cast(unsigned int, f);
  u += 0x7FFFu + ((u >> 16) & 1u);
  return (unsigned short)(u >> 16);
}

__device__ __forceinline__ void load16_to_lds(const void* g, void* lds) {
  __builtin_amdgcn_global_load_lds(
      (const __attribute__((address_space(1))) unsigned int*)g,
      (__attribute__((address_space(3))) unsigned int*)lds,
      16, 0, 0);
}

// ---------- kernel 0: sentinel (only if ws too small) ----------
__global__ void sentinel_kernel(float* out) { out[0] = 1.0e6f; }

// ---------- kernel 3: recurrence + folded pre-phase (R18) ----------
// Two-dispatch pipeline: this kernel absorbs the old xwcvt dispatch.
// Pre-phase per WG (c=blk&15, g=blk>>4):
//  (0) zero OWN 128 hcomb slots (both parities). Pollers spin on stale tags
//      (255/256 != wanted 0) until zeroes land during the ~50us pre-phase —
//      no ABA (audited: t>=1 polls transitively require owner's zero done).
//  (1) lm_W f32->bf16 grid-stride (196 MB, ~31us BW across 256 WGs).
//  (2) OWN xw tile (256t x 64j, K=512, f32 — R16: MUST be f32) into LDS:
//      thread (wave tg, lane j'): 16 t's; emb loads wave-uniform (broadcast);
//      Wx window 4KB L1-resident; 16 named scalar accs (no alloca).
// Then the PROVEN 457us loop, xv read from LDS instead of global xw.
__global__ __launch_bounds__(1024, 4) void rec_kernel(const float* __restrict__ Wh,
                                                      const int* __restrict__ tok,
                                                      const float* __restrict__ emb,
                                                      const float* __restrict__ Wx,
                                                      const float* __restrict__ bias,
                                                      const float* __restrict__ lmW,
                                                      unsigned short* __restrict__ lmW_bf,
                                                      unsigned long long* hcomb,  // [2][16][1024]
                                                      unsigned short* __restrict__ h_all) {
  int c = blockIdx.x & 15;
  int g = blockIdx.x >> 4;
  int tid = threadIdx.x;
  int w = tid >> 6;
  int l = tid & 63;
  int j = g * 64 + l;

  __shared__ float xwtile[256 * 64];  // 64 KB
  __shared__ float hs[16][64];
  __shared__ float pbuf[16][64];

  // --- pre-phase 0: zero own hcomb slots (unblocks the chain's t=0) ---
  if (tid < 128) {
    int p = tid >> 6, jj0 = g * 64 + (tid & 63);
    __hip_atomic_store(hcomb + (size_t)p * 16384 + c * 1024 + jj0, 0ull,
                       __ATOMIC_RELAXED, __HIP_MEMORY_SCOPE_AGENT);
  }

  // --- pre-phase 1: own xw tile (f32) into LDS ---
  {
    int jp = tid & 63;
    int tg = tid >> 6;
    int jj = g * 64 + jp;
    const float* wxrow = Wx + (size_t)jj * 512;
    float bv = bias[jj];
    int toks[16];
    #pragma unroll
    for (int s = 0; s < 16; ++s) toks[s] = tok[c * 256 + tg * 16 + s];
    float ax[16];
    #pragma unroll
    for (int s = 0; s < 16; ++s) ax[s] = bv;
    for (int kc = 0; kc < 512; kc += 4) {
      f32x4 wv = *(const f32x4*)(wxrow + kc);
      #pragma unroll
      for (int s = 0; s < 16; ++s) {
        f32x4 ev = *(const f32x4*)(emb + (size_t)toks[s] * 512 + kc);
        ax[s] = fmaf(wv[0], ev[0], ax[s]);
        ax[s] = fmaf(wv[1], ev[1], ax[s]);
        ax[s] = fmaf(wv[2], ev[2], ax[s]);
        ax[s] = fmaf(wv[3], ev[3], ax[s]);
      }
    }
    #pragma unroll
    for (int s = 0; s < 16; ++s) xwtile[(tg * 16 + s) * 64 + jp] = ax[s];
  }

  // --- pre-phase 2: lm_W f32 -> bf16 (grid-stride across all 256 WGs) ---
  {
    const int n8 = 32000 * 1024 / 8;   // 4,096,000 (2 float4 per index)
    int gstride = 256 * 1024;
    for (int i = blockIdx.x * 1024 + tid; i < n8; i += gstride) {
      float4 a = ((const float4*)lmW)[2 * i];
      float4 b = ((const float4*)lmW)[2 * i + 1];
      ushort4 lo, hi;
      lo.x = f32_to_bf16_rne(a.x); lo.y = f32_to_bf16_rne(a.y);
      lo.z = f32_to_bf16_rne(a.z); lo.w = f32_to_bf16_rne(a.w);
      hi.x = f32_to_bf16_rne(b.x); hi.y = f32_to_bf16_rne(b.y);
      hi.z = f32_to_bf16_rne(b.z); hi.w = f32_to_bf16_rne(b.w);
      ((ushort4*)lmW_bf)[2 * i] = lo;
      ((ushort4*)lmW_bf)[2 * i + 1] = hi;
    }
  }
  __syncthreads();

  // --- weights into registers (after pre-phase to keep its VGPR budget) ---
  const float* wb = Wh + (size_t)j * 1024 + w * 64;
#define LDW(i) f32x4 w##i = *(const f32x4*)(wb + i * 4);
  LDW(0) LDW(1) LDW(2) LDW(3) LDW(4) LDW(5) LDW(6) LDW(7)
  LDW(8) LDW(9) LDW(10) LDW(11) LDW(12) LDW(13) LDW(14) LDW(15)
#undef LDW

  unsigned long long* hc0 = hcomb + (size_t)c * 1024;
  unsigned long long* hc1 = hcomb + 16 * 1024 + (size_t)c * 1024;
  bool writer = (w == 0);
  float prevh = 0.f;

  for (int t = 0; t < 256; ++t) {
    float xv = 0.f;
    int tkn = 1;
    if (writer) {
      xv = xwtile[t * 64 + l];   // LDS (was global xw)
      tkn = tok[c * 256 + t];
    }
    unsigned long long* src = ((t & 1) ? hc1 : hc0) + tid;
    unsigned long long v;
    int guard = 0;
    do {
      v = __hip_atomic_load(src, __ATOMIC_RELAXED, __HIP_MEMORY_SCOPE_AGENT);
      if ((unsigned int)(v >> 32) == (unsigned int)t) break;
      __builtin_amdgcn_s_sleep(1);
    } while (++guard < (1 << 20));  // fail loud, not hung
    hs[w][l] = __builtin_bit_cast(float, (unsigned int)v);
    __asm__ volatile("s_waitcnt lgkmcnt(0)" ::: "memory");  // wave-local share

    const float* hp = &hs[w][0];
    f32x4 a0 = {0.f, 0.f, 0.f, 0.f}, a1 = a0, a2 = a0, a3 = a0;
#define FMAI(i, acc) { f32x4 h4 = *(const f32x4*)(hp + i * 4); acc += w##i * h4; }
    FMAI(0, a0) FMAI(1, a1) FMAI(2, a2) FMAI(3, a3)
    FMAI(4, a0) FMAI(5, a1) FMAI(6, a2) FMAI(7, a3)
    FMAI(8, a0) FMAI(9, a1) FMAI(10, a2) FMAI(11, a3)
    FMAI(12, a0) FMAI(13, a1) FMAI(14, a2) FMAI(15, a3)
#undef FMAI
    f32x4 aa = (a0 + a1) + (a2 + a3);
    pbuf[w][l] = (aa[0] + aa[1]) + (aa[2] + aa[3]);
    __asm__ volatile("s_waitcnt lgkmcnt(0)\n\ts_barrier" ::: "memory");

    if (writer) {
      float s = 0.f;
      #pragma unroll
      for (int q = 0; q < 16; ++q) s += pbuf[q][l];
      float hnew;
      if (tkn != PAD_IDX) {
        float pre = xv + s;
        float e = __builtin_amdgcn_exp2f(pre * 2.8853900817779268f);  // exp(2x)
        hnew = 1.0f - 2.0f / (e + 1.0f);                              // tanh(x)
      } else {
        hnew = prevh;  // register: race-free old h of own row
      }
      prevh = hnew;
      unsigned long long pv =
          ((unsigned long long)(unsigned int)(t + 1) << 32) |
          (unsigned long long)__builtin_bit_cast(unsigned int, hnew);
      __hip_atomic_store((((t + 1) & 1) ? hc1 : hc0) + j, pv,
                         __ATOMIC_RELAXED, __HIP_MEMORY_SCOPE_AGENT);
      h_all[((size_t)c * 256 + t) * 1024 + j] = f32_to_bf16_rne(hnew);
    }
  }
}

// ---------- kernel 4: logits GEMM — 8-phase schedule (R15/R17, unchanged) ----------
__global__ __launch_bounds__(512) void gemm_kernel(const unsigned short* __restrict__ A,
                                                   const unsigned short* __restrict__ B,
                                                   float* __restrict__ C) {
  __shared__ unsigned short lds[2 * 32768];
  int tid = threadIdx.x;
  int lane = tid & 63, wave = tid >> 6;
  int bid = blockIdx.x;
  int x = bid & 7;
  int r = bid >> 3;
  int tm = 2 * x + (r & 1);
  int tn = r >> 1;
  int r0 = tm * 256, c0 = tn * 256;
  int wm = wave >> 2, wn = wave & 3;

  auto SH = [&](int kt, int st, int mat, int half) {
    unsigned short* buf = (unsigned short*)lds + st * 32768 + mat * 16384 + half * 8192;
    const unsigned short* src = mat ? (B + (size_t)(c0 + half * 128) * 1024)
                                    : (A + (size_t)(r0 + half * 128) * 1024);
    #pragma unroll
    for (int i = 0; i < 2; ++i) {
      int slot = i * 512 + tid;
      int row = slot >> 3, sg = slot & 7;
      int kg = sg ^ (row & 7);
      const unsigned short* g = src + (size_t)row * 1024 + kt * 64 + kg * 8;
      load16_to_lds(g, &buf[(i * 512 + wave * 64) * 8]);
    }
  };

  f32x4 zero = {0.f, 0.f, 0.f, 0.f};
  f32x4 acc[8][4];
  #pragma unroll
  for (int i = 0; i < 8; ++i)
    #pragma unroll
    for (int jx = 0; jx < 4; ++jx) acc[i][jx] = zero;

  SH(0, 0, 0, 0); SH(0, 0, 0, 1); SH(0, 0, 1, 0); SH(0, 0, 1, 1);
  SH(1, 1, 0, 0); SH(1, 1, 0, 1);
  __asm__ volatile("s_waitcnt vmcnt(0)" ::: "memory");
  __builtin_amdgcn_s_barrier();

  for (int kt = 0; kt < 16; ++kt) {
    int st = kt & 1;
    const char* bufA = (const char*)((const unsigned short*)lds + st * 32768);
    const char* bufB = bufA + 32768;
    int ktB = kt + 1 > 15 ? 15 : kt + 1;
    int ktA = kt + 2 > 15 ? 15 : kt + 2;
    int kb0 = (lane >> 4) * 16;
    int kb1 = 64 + kb0;
    short8 af0[8], af1[8], bf0[4], bf1[4];

    #pragma unroll
    for (int i = 0; i < 8; ++i) {
      int rowa = wm * 128 + i * 16 + (lane & 15);
      af0[i] = *(const short8*)(bufA + rowa * 128 + (kb0 ^ ((rowa & 7) << 4)));
    }
    #pragma unroll
    for (int jx = 0; jx < 2; ++jx) {
      int rowb = wn * 64 + jx * 16 + (lane & 15);
      bf0[jx] = *(const short8*)(bufB + rowb * 128 + (kb0 ^ ((rowb & 7) << 4)));
    }
    SH(ktB, st ^ 1, 1, 0);
    __builtin_amdgcn_s_barrier();
    __asm__ volatile("s_waitcnt lgkmcnt(0)" ::: "memory");
    __builtin_amdgcn_s_setprio(1);
    #pragma unroll
    for (int i = 0; i < 8; ++i)
      #pragma unroll
      for (int jx = 0; jx < 2; ++jx)
        acc[i][jx] = __builtin_amdgcn_mfma_f32_16x16x32_bf16(af0[i], bf0[jx], acc[i][jx], 0, 0, 0);
    __builtin_amdgcn_s_setprio(0);
    __builtin_amdgcn_s_barrier();

    #pragma unroll
    for (int jx = 2; jx < 4; ++jx) {
      int rowb = wn * 64 + jx * 16 + (lane & 15);
      bf0[jx] = *(const short8*)(bufB + rowb * 128 + (kb0 ^ ((rowb & 7) << 4)));
    }
    SH(ktB, st ^ 1, 1, 1);
    __builtin_amdgcn_s_barrier();
    __asm__ volatile("s_waitcnt lgkmcnt(0)" ::: "memory");
    __builtin_amdgcn_s_setprio(1);
    #pragma unroll
    for (int i = 0; i < 8; ++i)
      #pragma unroll
      for (int jx = 2; jx < 4; ++jx)
        acc[i][jx] = __builtin_amdgcn_mfma_f32_16x16x32_bf16(af0[i], bf0[jx], acc[i][jx], 0, 0, 0);
    __builtin_amdgcn_s_setprio(0);
    __builtin_amdgcn_s_barrier();

    #pragma unroll
    for (int i = 0; i < 8; ++i) {
      int rowa = wm * 128 + i * 16 + (lane & 15);
      af1[i] = *(const short8*)(bufA + rowa * 128 + (kb1 ^ ((rowa & 7) << 4)));
    }
    #pragma unroll
    for (int jx = 0; jx < 2; ++jx) {
      int rowb = wn * 64 + jx * 16 + (lane & 15);
      bf1[jx] = *(const short8*)(bufB + rowb * 128 + (kb1 ^ ((rowb & 7) << 4)));
    }
    __builtin_amdgcn_s_barrier();
    __asm__ volatile("s_waitcnt lgkmcnt(0)" ::: "memory");
    __builtin_amdgcn_s_setprio(1);
    #pragma unroll
    for (int i = 0; i < 8; ++i)
      #pragma unroll
      for (int jx = 0; jx < 2; ++jx)
        acc[i][jx] = __builtin_amdgcn_mfma_f32_16x16x32_bf16(af1[i], bf1[jx], acc[i][jx], 0, 0, 0);
    __builtin_amdgcn_s_setprio(0);
    __builtin_amdgcn_s_barrier();

    #pragma unroll
    for (int jx = 2; jx < 4; ++jx) {
      int rowb = wn * 64 + jx * 16 + (lane & 15);
      bf1[jx] = *(const short8*)(bufB + rowb * 128 + (kb1 ^ ((rowb & 7) << 4)));
    }
    SH(ktA, st, 0, 0);
    SH(ktA, st, 0, 1);
    __builtin_amdgcn_s_barrier();
    __asm__ volatile("s_waitcnt lgkmcnt(0)" ::: "memory");
    __builtin_amdgcn_s_setprio(1);
    #pragma unroll
    for (int i = 0; i < 8; ++i)
      #pragma unroll
      for (int jx = 2; jx < 4; ++jx)
        acc[i][jx] = __builtin_amdgcn_mfma_f32_16x16x32_bf16(af1[i], bf1[jx], acc[i][jx], 0, 0, 0);
    __builtin_amdgcn_s_setprio(0);
    __asm__ volatile("s_waitcnt vmcnt(4)" ::: "memory");
    __builtin_amdgcn_s_barrier();
  }
  __asm__ volatile("s_waitcnt vmcnt(0)" ::: "memory");

  int rbase = r0 + wm * 128 + (lane >> 4) * 4;
  int cbase = c0 + wn * 64 + (lane & 15);
  #pragma unroll
  for (int i = 0; i < 8; ++i)
    #pragma unroll
    for (int jx = 0; jx < 4; ++jx)
      #pragma unroll
      for (int q = 0; q < 4; ++q)
        C[(size_t)(rbase + i * 16 + q) * 32000 + cbase + jx * 16] = acc[i][jx][q];
}

// ---------- launch ----------
extern "C" void kernel_launch(void* const* d_in, const int* in_sizes, int n_in,
                              void* d_out, int out_size, void* d_ws, size_t ws_size,
                              hipStream_t stream) {
  const int* tok = (const int*)d_in[0];
  const float* emb = (const float*)d_in[1];
  const float* Wx = (const float*)d_in[2];
  const float* Wh = (const float*)d_in[3];
  const float* bias = (const float*)d_in[4];
  const float* lmW = (const float*)d_in[5];
  float* out = (float*)d_out;

  const size_t OFF_LMW = 0;                       // bf16 lm_W: 65,536,000
  const size_t OFF_HALL = 65536000;               // bf16 h_all: 8,388,608
  const size_t OFF_HCMB = OFF_HALL + 8388608;     // u64 hcomb: 262,144
  const size_t NEED = OFF_HCMB + 262144;
  if (ws_size < NEED) {
    sentinel_kernel<<<1, 1, 0, stream>>>(out);
    return;
  }
  char* ws = (char*)d_ws;
  unsigned short* lmW_bf = (unsigned short*)(ws + OFF_LMW);
  unsigned short* h_all = (unsigned short*)(ws + OFF_HALL);
  unsigned long long* hcomb = (unsigned long long*)(ws + OFF_HCMB);

  // hcomb zeroing + xw + cvt all inside rec pre-phase — every call (graph replay)
  rec_kernel<<<256, 1024, 0, stream>>>(Wh, tok, emb, Wx, bias, lmW, lmW_bf,
                                       hcomb, h_all);
  gemm_kernel<<<2000, 512, 0, stream>>>(h_all, lmW_bf, out);
}

// Round 19
// 862.619 us; speedup vs baseline: 1.2969x; 1.2969x over previous
//
#include <hip/hip_runtime.h>

#define PAD_IDX 0

typedef __attribute__((ext_vector_type(8))) short short8;
typedef __attribute__((ext_vector_type(4))) float f32x4;

// ---------- helpers ----------
__device__ __forceinline__ unsigned short f32_to_bf16_rne(float f) {
  unsigned int u = __builtin_bit_cast(unsigned int, f);
  u += 0x7FFFu + ((u >> 16) & 1u);
  return (unsigned short)(u >> 16);
}

__device__ __forceinline__ void load16_to_lds(const void* g, void* lds) {
  __builtin_amdgcn_global_load_lds(
      (const __attribute__((address_space(1))) unsigned int*)g,
      (__attribute__((address_space(3))) unsigned int*)lds,
      16, 0, 0);
}

// ---------- kernel 0: sentinel (only if ws too small) ----------
__global__ void sentinel_kernel(float* out) { out[0] = 1.0e6f; }

// ---------- kernel 1: merged xw(f32) + cvt + hcomb-zero (R17-proven 862.7) ----------
// R16 lesson: xw MUST stay f32 (bf16 pre-activation error propagates ~linearly
// through the 256-step tanh chain). R18 lesson: do NOT fold xw into rec — the
// fold replaces this kernel's coalesced LDS-staged tiling with a strided
// scalar walk (L1 thrash, latency-bound, +398us).
__global__ __launch_bounds__(256) void xwcvt_kernel(const int* __restrict__ tok,
                                                    const float* __restrict__ emb,
                                                    const float* __restrict__ Wx,
                                                    const float* __restrict__ bias,
                                                    float* __restrict__ xw,
                                                    const float* __restrict__ lmW,
                                                    unsigned short* __restrict__ lmW_bf,
                                                    unsigned long long* hcomb) {
  int tid = threadIdx.x;
  if (blockIdx.x >= 1024) {
    if (blockIdx.x < 1040) {  // hcomb zero: 16 blk x 256 thr x 8 u64 = 262144 B
      size_t base = ((size_t)(blockIdx.x - 1024) * 256 + tid) * 8;
      #pragma unroll
      for (int q = 0; q < 8; ++q) hcomb[base + q] = 0ull;
    }
    const int n8 = 32000 * 1024 / 8;
    int stride = 512 * 256;
    for (int i = (blockIdx.x - 1024) * 256 + tid; i < n8; i += stride) {
      float4 a = ((const float4*)lmW)[2 * i];
      float4 b = ((const float4*)lmW)[2 * i + 1];
      ushort4 lo, hi;
      lo.x = f32_to_bf16_rne(a.x); lo.y = f32_to_bf16_rne(a.y);
      lo.z = f32_to_bf16_rne(a.z); lo.w = f32_to_bf16_rne(a.w);
      hi.x = f32_to_bf16_rne(b.x); hi.y = f32_to_bf16_rne(b.y);
      hi.z = f32_to_bf16_rne(b.z); hi.w = f32_to_bf16_rne(b.w);
      ((ushort4*)lmW_bf)[2 * i] = lo;
      ((ushort4*)lmW_bf)[2 * i + 1] = hi;
    }
    return;
  }
  __shared__ float At[32][68];
  __shared__ float Bt[32][68];
  __shared__ int stok[64];
  int tm = blockIdx.x & 63;
  int tn = blockIdx.x >> 6;
  int r0 = tm * 64, j0 = tn * 64;
  if (tid < 64) stok[tid] = tok[r0 + tid];
  int tx = tid & 15, ty = tid >> 4;
  float acc[4][4] = {};
  for (int kt = 0; kt < 512; kt += 32) {
    __syncthreads();
    #pragma unroll
    for (int ii = 0; ii < 2; ++ii) {
      int idx = tid * 2 + ii;
      int m = idx >> 3, fv = idx & 7;
      float4 va = *(const float4*)&emb[(size_t)stok[m] * 512 + kt + fv * 4];
      float4 vb = *(const float4*)&Wx[(size_t)(j0 + m) * 512 + kt + fv * 4];
      At[fv * 4 + 0][m] = va.x; At[fv * 4 + 1][m] = va.y;
      At[fv * 4 + 2][m] = va.z; At[fv * 4 + 3][m] = va.w;
      Bt[fv * 4 + 0][m] = vb.x; Bt[fv * 4 + 1][m] = vb.y;
      Bt[fv * 4 + 2][m] = vb.z; Bt[fv * 4 + 3][m] = vb.w;
    }
    __syncthreads();
    #pragma unroll
    for (int k = 0; k < 32; ++k) {
      float4 a4 = *(const float4*)&At[k][ty * 4];
      float4 b4 = *(const float4*)&Bt[k][tx * 4];
      float av[4] = {a4.x, a4.y, a4.z, a4.w};
      float bv[4] = {b4.x, b4.y, b4.z, b4.w};
      #pragma unroll
      for (int i = 0; i < 4; ++i)
        #pragma unroll
        for (int jj = 0; jj < 4; ++jj) acc[i][jj] = fmaf(av[i], bv[jj], acc[i][jj]);
    }
  }
  #pragma unroll
  for (int i = 0; i < 4; ++i) {
    size_t row = (size_t)(r0 + ty * 4 + i) * 1024 + j0 + tx * 4;
    #pragma unroll
    for (int jj = 0; jj < 4; ++jj)
      xw[row + jj] = acc[i][jj] + bias[j0 + tx * 4 + jj];
  }
}

// ---------- kernel 3: recurrence (exact R10 structure — proven 453-457 us x5) ----------
__global__ __launch_bounds__(1024, 4) void rec_kernel(const float* __restrict__ Wh,
                                                      const float* __restrict__ xw,
                                                      const int* __restrict__ tok,
                                                      unsigned long long* hcomb,  // [2][16][1024]
                                                      unsigned short* __restrict__ h_all) {
  int c = blockIdx.x & 15;
  int g = blockIdx.x >> 4;
  int tid = threadIdx.x;
  int w = tid >> 6;
  int l = tid & 63;
  int j = g * 64 + l;

  const float* wb = Wh + (size_t)j * 1024 + w * 64;
#define LDW(i) f32x4 w##i = *(const f32x4*)(wb + i * 4);
  LDW(0) LDW(1) LDW(2) LDW(3) LDW(4) LDW(5) LDW(6) LDW(7)
  LDW(8) LDW(9) LDW(10) LDW(11) LDW(12) LDW(13) LDW(14) LDW(15)
#undef LDW

  __shared__ float hs[16][64];
  __shared__ float pbuf[16][64];
  unsigned long long* hc0 = hcomb + (size_t)c * 1024;
  unsigned long long* hc1 = hcomb + 16 * 1024 + (size_t)c * 1024;
  bool writer = (w == 0);
  float prevh = 0.f;

  for (int t = 0; t < 256; ++t) {
    float xv = 0.f;
    int tkn = 1;
    if (writer) {
      xv = xw[((size_t)c * 256 + t) * 1024 + j];
      tkn = tok[c * 256 + t];
    }
    unsigned long long* src = ((t & 1) ? hc1 : hc0) + tid;
    unsigned long long v;
    int guard = 0;
    do {
      v = __hip_atomic_load(src, __ATOMIC_RELAXED, __HIP_MEMORY_SCOPE_AGENT);
      if ((unsigned int)(v >> 32) == (unsigned int)t) break;
      __builtin_amdgcn_s_sleep(1);
    } while (++guard < (1 << 20));  // fail loud, not hung
    hs[w][l] = __builtin_bit_cast(float, (unsigned int)v);
    __asm__ volatile("s_waitcnt lgkmcnt(0)" ::: "memory");  // wave-local share

    const float* hp = &hs[w][0];
    f32x4 a0 = {0.f, 0.f, 0.f, 0.f}, a1 = a0, a2 = a0, a3 = a0;
#define FMAI(i, acc) { f32x4 h4 = *(const f32x4*)(hp + i * 4); acc += w##i * h4; }
    FMAI(0, a0) FMAI(1, a1) FMAI(2, a2) FMAI(3, a3)
    FMAI(4, a0) FMAI(5, a1) FMAI(6, a2) FMAI(7, a3)
    FMAI(8, a0) FMAI(9, a1) FMAI(10, a2) FMAI(11, a3)
    FMAI(12, a0) FMAI(13, a1) FMAI(14, a2) FMAI(15, a3)
#undef FMAI
    f32x4 aa = (a0 + a1) + (a2 + a3);
    pbuf[w][l] = (aa[0] + aa[1]) + (aa[2] + aa[3]);
    __asm__ volatile("s_waitcnt lgkmcnt(0)\n\ts_barrier" ::: "memory");

    if (writer) {
      float s = 0.f;
      #pragma unroll
      for (int q = 0; q < 16; ++q) s += pbuf[q][l];
      float hnew;
      if (tkn != PAD_IDX) {
        float pre = xv + s;
        float e = __builtin_amdgcn_exp2f(pre * 2.8853900817779268f);  // exp(2x)
        hnew = 1.0f - 2.0f / (e + 1.0f);                              // tanh(x)
      } else {
        hnew = prevh;  // register: race-free old h of own row
      }
      prevh = hnew;
      unsigned long long pv =
          ((unsigned long long)(unsigned int)(t + 1) << 32) |
          (unsigned long long)__builtin_bit_cast(unsigned int, hnew);
      __hip_atomic_store((((t + 1) & 1) ? hc1 : hc0) + j, pv,
                         __ATOMIC_RELAXED, __HIP_MEMORY_SCOPE_AGENT);
      h_all[((size_t)c * 256 + t) * 1024 + j] = f32_to_bf16_rne(hnew);
    }
  }
}

// ---------- kernel 4: logits GEMM — 8-phase schedule (R15/R17, unchanged) ----------
__global__ __launch_bounds__(512) void gemm_kernel(const unsigned short* __restrict__ A,
                                                   const unsigned short* __restrict__ B,
                                                   float* __restrict__ C) {
  __shared__ unsigned short lds[2 * 32768];
  int tid = threadIdx.x;
  int lane = tid & 63, wave = tid >> 6;
  int bid = blockIdx.x;
  int x = bid & 7;
  int r = bid >> 3;
  int tm = 2 * x + (r & 1);
  int tn = r >> 1;
  int r0 = tm * 256, c0 = tn * 256;
  int wm = wave >> 2, wn = wave & 3;

  auto SH = [&](int kt, int st, int mat, int half) {
    unsigned short* buf = (unsigned short*)lds + st * 32768 + mat * 16384 + half * 8192;
    const unsigned short* src = mat ? (B + (size_t)(c0 + half * 128) * 1024)
                                    : (A + (size_t)(r0 + half * 128) * 1024);
    #pragma unroll
    for (int i = 0; i < 2; ++i) {
      int slot = i * 512 + tid;
      int row = slot >> 3, sg = slot & 7;
      int kg = sg ^ (row & 7);
      const unsigned short* g = src + (size_t)row * 1024 + kt * 64 + kg * 8;
      load16_to_lds(g, &buf[(i * 512 + wave * 64) * 8]);
    }
  };

  f32x4 zero = {0.f, 0.f, 0.f, 0.f};
  f32x4 acc[8][4];
  #pragma unroll
  for (int i = 0; i < 8; ++i)
    #pragma unroll
    for (int jx = 0; jx < 4; ++jx) acc[i][jx] = zero;

  SH(0, 0, 0, 0); SH(0, 0, 0, 1); SH(0, 0, 1, 0); SH(0, 0, 1, 1);
  SH(1, 1, 0, 0); SH(1, 1, 0, 1);
  __asm__ volatile("s_waitcnt vmcnt(0)" ::: "memory");
  __builtin_amdgcn_s_barrier();

  for (int kt = 0; kt < 16; ++kt) {
    int st = kt & 1;
    const char* bufA = (const char*)((const unsigned short*)lds + st * 32768);
    const char* bufB = bufA + 32768;
    int ktB = kt + 1 > 15 ? 15 : kt + 1;
    int ktA = kt + 2 > 15 ? 15 : kt + 2;
    int kb0 = (lane >> 4) * 16;
    int kb1 = 64 + kb0;
    short8 af0[8], af1[8], bf0[4], bf1[4];

    #pragma unroll
    for (int i = 0; i < 8; ++i) {
      int rowa = wm * 128 + i * 16 + (lane & 15);
      af0[i] = *(const short8*)(bufA + rowa * 128 + (kb0 ^ ((rowa & 7) << 4)));
    }
    #pragma unroll
    for (int jx = 0; jx < 2; ++jx) {
      int rowb = wn * 64 + jx * 16 + (lane & 15);
      bf0[jx] = *(const short8*)(bufB + rowb * 128 + (kb0 ^ ((rowb & 7) << 4)));
    }
    SH(ktB, st ^ 1, 1, 0);
    __builtin_amdgcn_s_barrier();
    __asm__ volatile("s_waitcnt lgkmcnt(0)" ::: "memory");
    __builtin_amdgcn_s_setprio(1);
    #pragma unroll
    for (int i = 0; i < 8; ++i)
      #pragma unroll
      for (int jx = 0; jx < 2; ++jx)
        acc[i][jx] = __builtin_amdgcn_mfma_f32_16x16x32_bf16(af0[i], bf0[jx], acc[i][jx], 0, 0, 0);
    __builtin_amdgcn_s_setprio(0);
    __builtin_amdgcn_s_barrier();

    #pragma unroll
    for (int jx = 2; jx < 4; ++jx) {
      int rowb = wn * 64 + jx * 16 + (lane & 15);
      bf0[jx] = *(const short8*)(bufB + rowb * 128 + (kb0 ^ ((rowb & 7) << 4)));
    }
    SH(ktB, st ^ 1, 1, 1);
    __builtin_amdgcn_s_barrier();
    __asm__ volatile("s_waitcnt lgkmcnt(0)" ::: "memory");
    __builtin_amdgcn_s_setprio(1);
    #pragma unroll
    for (int i = 0; i < 8; ++i)
      #pragma unroll
      for (int jx = 2; jx < 4; ++jx)
        acc[i][jx] = __builtin_amdgcn_mfma_f32_16x16x32_bf16(af0[i], bf0[jx], acc[i][jx], 0, 0, 0);
    __builtin_amdgcn_s_setprio(0);
    __builtin_amdgcn_s_barrier();

    #pragma unroll
    for (int i = 0; i < 8; ++i) {
      int rowa = wm * 128 + i * 16 + (lane & 15);
      af1[i] = *(const short8*)(bufA + rowa * 128 + (kb1 ^ ((rowa & 7) << 4)));
    }
    #pragma unroll
    for (int jx = 0; jx < 2; ++jx) {
      int rowb = wn * 64 + jx * 16 + (lane & 15);
      bf1[jx] = *(const short8*)(bufB + rowb * 128 + (kb1 ^ ((rowb & 7) << 4)));
    }
    __builtin_amdgcn_s_barrier();
    __asm__ volatile("s_waitcnt lgkmcnt(0)" ::: "memory");
    __builtin_amdgcn_s_setprio(1);
    #pragma unroll
    for (int i = 0; i < 8; ++i)
      #pragma unroll
      for (int jx = 0; jx < 2; ++jx)
        acc[i][jx] = __builtin_amdgcn_mfma_f32_16x16x32_bf16(af1[i], bf1[jx], acc[i][jx], 0, 0, 0);
    __builtin_amdgcn_s_setprio(0);
    __builtin_amdgcn_s_barrier();

    #pragma unroll
    for (int jx = 2; jx < 4; ++jx) {
      int rowb = wn * 64 + jx * 16 + (lane & 15);
      bf1[jx] = *(const short8*)(bufB + rowb * 128 + (kb1 ^ ((rowb & 7) << 4)));
    }
    SH(ktA, st, 0, 0);
    SH(ktA, st, 0, 1);
    __builtin_amdgcn_s_barrier();
    __asm__ volatile("s_waitcnt lgkmcnt(0)" ::: "memory");
    __builtin_amdgcn_s_setprio(1);
    #pragma unroll
    for (int i = 0; i < 8; ++i)
      #pragma unroll
      for (int jx = 2; jx < 4; ++jx)
        acc[i][jx] = __builtin_amdgcn_mfma_f32_16x16x32_bf16(af1[i], bf1[jx], acc[i][jx], 0, 0, 0);
    __builtin_amdgcn_s_setprio(0);
    __asm__ volatile("s_waitcnt vmcnt(4)" ::: "memory");
    __builtin_amdgcn_s_barrier();
  }
  __asm__ volatile("s_waitcnt vmcnt(0)" ::: "memory");

  int rbase = r0 + wm * 128 + (lane >> 4) * 4;
  int cbase = c0 + wn * 64 + (lane & 15);
  #pragma unroll
  for (int i = 0; i < 8; ++i)
    #pragma unroll
    for (int jx = 0; jx < 4; ++jx)
      #pragma unroll
      for (int q = 0; q < 4; ++q)
        C[(size_t)(rbase + i * 16 + q) * 32000 + cbase + jx * 16] = acc[i][jx][q];
}

// ---------- launch ----------
extern "C" void kernel_launch(void* const* d_in, const int* in_sizes, int n_in,
                              void* d_out, int out_size, void* d_ws, size_t ws_size,
                              hipStream_t stream) {
  const int* tok = (const int*)d_in[0];
  const float* emb = (const float*)d_in[1];
  const float* Wx = (const float*)d_in[2];
  const float* Wh = (const float*)d_in[3];
  const float* bias = (const float*)d_in[4];
  const float* lmW = (const float*)d_in[5];
  float* out = (float*)d_out;

  const size_t OFF_LMW = 0;                       // bf16 lm_W: 65,536,000
  const size_t OFF_XW = 65536000;                 // f32 xw:   16,777,216
  const size_t OFF_HALL = OFF_XW + 16777216;      // bf16 h_all: 8,388,608
  const size_t OFF_HCMB = OFF_HALL + 8388608;     // u64 hcomb: 262,144
  const size_t NEED = OFF_HCMB + 262144;
  if (ws_size < NEED) {
    sentinel_kernel<<<1, 1, 0, stream>>>(out);
    return;
  }
  char* ws = (char*)d_ws;
  unsigned short* lmW_bf = (unsigned short*)(ws + OFF_LMW);
  float* xw = (float*)(ws + OFF_XW);
  unsigned short* h_all = (unsigned short*)(ws + OFF_HALL);
  unsigned long long* hcomb = (unsigned long long*)(ws + OFF_HCMB);

  // hcomb zeroing folded into xwcvt (blocks 1024..1039) — every call (graph replay)
  xwcvt_kernel<<<1536, 256, 0, stream>>>(tok, emb, Wx, bias, xw, lmW, lmW_bf, hcomb);
  rec_kernel<<<256, 1024, 0, stream>>>(Wh, xw, tok, hcomb, h_all);
  gemm_kernel<<<2000, 512, 0, stream>>>(h_all, lmW_bf, out);
}